// Round 1
// baseline (3320.624 us; speedup 1.0000x reference)
//
#include <hip/hip_runtime.h>

#define NN   6144
#define MMY  6144
#define MP1  6145
#define KC   4              // columns per lane
#define WCH  (KC * 64)      // columns per wave = 256
#define GCH  (MMY / WCH)    // 24 waves / workgroups
#define RT   32             // rows per inter-wave handoff tile
#define FINF 99999.0f

__device__ __forceinline__ int clampi(int i) {
    return i < 0 ? 0 : (i >= NN ? NN - 1 : i);
}

// Lane-systolic DTW: wave g owns columns [g*WCH, (g+1)*WCH); lane l owns KC
// contiguous columns and processes row (s - l) at step s. Carry between lanes
// via shfl_up of last step's segment-end value; carry between waves via d_out
// readback (re-squared) gated by an agent-scope flag every RT rows.
__global__ void __launch_bounds__(64) dtw_main(const float* __restrict__ x,
                                               const float* __restrict__ y,
                                               float* __restrict__ out,
                                               int* flags) {
    const int g    = blockIdx.x;
    const int lane = threadIdx.x;
    const int j0   = g * WCH;          // wave's first y-column
    const int c0   = j0 + lane * KC;   // lane's first y-column

    float yv[KC], prev[KC];
#pragma unroll
    for (int q = 0; q < KC; ++q) {
        yv[q]   = y[c0 + q];
        prev[q] = FINF;                // dtw[0][c0+q+1] = INF
    }
    // pl = dtw[i_prev_row][c0]  (column left of lane's segment, previous row)
    float pl    = (c0 == 0) ? 0.0f : FINF;   // dtw[0][0]=0, else INF
    float rlast = FINF;   // lane's segment-end r from previous step
    float vbuf  = FINF;   // lane j<RT holds left-boundary carry for row tileBase+j

    // x prefetch pipeline (distance 2); loads are coalesced across lanes
    float xn1 = x[clampi(0 - lane)];
    float xn2 = x[clampi(1 - lane)];

    // output offset for (row i+1, col c0+1), i = s - lane; advance by MP1/step
    int off = (1 - lane) * MP1 + c0 + 1;

    for (int s = 0; s < NN + 63; ++s) {
        const int i = s - lane;        // this lane's row index (x index)

        // ---- consumer: fetch RT left-boundary carries at tile start ----
        if (g != 0 && (s & (RT - 1)) == 0 && s < NN) {
            const int want = (s / RT) + 1;
            while (__hip_atomic_load(&flags[g - 1], __ATOMIC_ACQUIRE,
                                     __HIP_MEMORY_SCOPE_AGENT) < want) {
                __builtin_amdgcn_s_sleep(1);
            }
            float tv = FINF;
            if (lane < RT) tv = out[(s + lane + 1) * MP1 + j0]; // sqrt(dtw[row+1][j0])
            vbuf = tv * tv;                                     // undo sqrt
        }

        // ---- per-step carries ----
        const float up = __shfl_up(rlast, 1);          // left lane's r, same row
        const float v0 = __shfl(vbuf, s & (RT - 1));   // left wave's r, row s (lane0)
        const float v  = (lane == 0) ? ((g == 0) ? FINF : v0) : up;

        const float xi = xn1;
        xn1 = xn2;
        xn2 = x[clampi(s + 2 - lane)];

        const bool active = (i >= 0) && (i < NN);

        // ---- KC serial cells: r = c + min3(left, up, diag) ----
        float r = v, pm1 = pl;
        float nv[KC];
#pragma unroll
        for (int q = 0; q < KC; ++q) {
            const float d = xi - yv[q];
            const float c = d * d;
            r   = c + fminf(fminf(r, prev[q]), pm1);
            pm1 = prev[q];
            nv[q] = r;
        }

        if (active) {
#pragma unroll
            for (int q = 0; q < KC; ++q) {
                prev[q]      = nv[q];
                out[off + q] = __builtin_amdgcn_sqrtf(nv[q]);
            }
            rlast = r;
            pl    = v;
        }
        off += MP1;

        // ---- producer: publish flag every RT completed boundary rows ----
        const int done = s - 62;   // rows fully completed by lane 63
        if (g != GCH - 1 && done > 0 && (done & (RT - 1)) == 0) {
            __threadfence();       // agent-scope release of prior out[] stores
            if (lane == 0)
                __hip_atomic_store(&flags[g], done / RT, __ATOMIC_RELEASE,
                                   __HIP_MEMORY_SCOPE_AGENT);
        }
    }
}

// Row 0 and column 0 sentinels: sqrt(INF), with out[0,0] = 0.
__global__ void dtw_edges(float* __restrict__ out) {
    const int idx = blockIdx.x * blockDim.x + threadIdx.x;
    const float e = __builtin_amdgcn_sqrtf(FINF);
    if (idx <= MMY) {
        out[idx] = (idx == 0) ? 0.0f : e;     // row 0
        if (idx >= 1) out[idx * MP1] = e;     // column 0
    }
}

extern "C" void kernel_launch(void* const* d_in, const int* in_sizes, int n_in,
                              void* d_out, int out_size, void* d_ws, size_t ws_size,
                              hipStream_t stream) {
    (void)in_sizes; (void)n_in; (void)out_size; (void)ws_size;
    const float* x = (const float*)d_in[0];
    const float* y = (const float*)d_in[1];
    float* out     = (float*)d_out;
    int* flags     = (int*)d_ws;

    // flags must start at 0 every call (d_ws is re-poisoned to 0xAA)
    hipMemsetAsync(flags, 0, GCH * sizeof(int), stream);
    dtw_edges<<<(MP1 + 255) / 256, 256, 0, stream>>>(out);
    dtw_main<<<GCH, 64, 0, stream>>>(x, y, out, flags);
}